// Round 2
// baseline (260.557 us; speedup 1.0000x reference)
//
#include <hip/hip_runtime.h>
#include <cmath>

#define HW (512*512)
#define NSUB 2048            // 64 bins x 32 sub-bins
#define THREADS1 1024
#define BLKS_PER_IMG 32
#define PART_WORDS (3 * NSUB / 2)   // 3072 u32 per partial (u16-packed sub-bins)

__device__ __forceinline__ float fexp2(float x) { return __builtin_amdgcn_exp2f(x); }
__device__ __forceinline__ float flog2(float x) { return __builtin_amdgcn_logf(x); }

// Fused: RGB -> Lab -> integer sub-bin counting into dual wave-parity LDS
// tables; per-block u16-packed partial stored to ws with plain stores; the
// last-arriving block per image (device-scope counter) re-reads the 32
// partials with agent-scope atomic loads (bypasses non-coherent per-XCD L2),
// does the 204-tap truncated-Gaussian conv -> 64 bins, normalizes, writes out.
// Reducers for early images overlap with count work of later images.
__global__ __launch_bounds__(THREADS1) void count_fused(const float* __restrict__ img,
                                                        unsigned* __restrict__ part,
                                                        unsigned* __restrict__ done,
                                                        float* __restrict__ out) {
    __shared__ unsigned sh[2][3 * NSUB];   // 48 KB (reused as float sub3[] by reducer)
    __shared__ float hb[3][64];
    __shared__ int lastFlag;
    const int tid = threadIdx.x;
    unsigned* flat = &sh[0][0];
    for (int i = tid; i < 2 * 3 * NSUB; i += THREADS1) flat[i] = 0u;
    __syncthreads();

    unsigned* h = sh[(tid >> 6) & 1];      // wave parity selects table

    const int b  = blockIdx.y;
    const int bx = blockIdx.x;
    const float* base = img + (size_t)b * 3u * HW;

    const int stride = BLKS_PER_IMG * THREADS1 * 4;
    for (int p = (bx * THREADS1 + tid) * 4; p < HW; p += stride) {
        float4 r4 = *reinterpret_cast<const float4*>(base + p);
        float4 g4 = *reinterpret_cast<const float4*>(base + p + HW);
        float4 b4 = *reinterpret_cast<const float4*>(base + p + 2 * HW);
        float rr[4] = {r4.x, r4.y, r4.z, r4.w};
        float gg[4] = {g4.x, g4.y, g4.z, g4.w};
        float bl[4] = {b4.x, b4.y, b4.z, b4.w};

        #pragma unroll
        for (int k = 0; k < 4; ++k) {
            // sRGB -> linear (log2 inputs provably >= 0.09: no denormal risk)
            float lr = (rr[k] > 0.04045f) ? fexp2(2.4f * flog2((rr[k] + 0.055f) * (1.0f / 1.055f))) : rr[k] * (1.0f / 12.92f);
            float lg = (gg[k] > 0.04045f) ? fexp2(2.4f * flog2((gg[k] + 0.055f) * (1.0f / 1.055f))) : gg[k] * (1.0f / 12.92f);
            float lb = (bl[k] > 0.04045f) ? fexp2(2.4f * flog2((bl[k] + 0.055f) * (1.0f / 1.055f))) : bl[k] * (1.0f / 12.92f);

            // XYZ with xn/zn folded into the matrix rows
            float x = 0.4339530f * lr + 0.3762197f * lg + 0.1898288f * lb; // x/0.950456
            float y = 0.2126710f * lr + 0.7151600f * lg + 0.0721690f * lb;
            float z = 0.0177578f * lr + 0.1094766f * lg + 0.8727661f * lb; // z/1.088754

            float fx = (x > 0.008856f) ? fexp2(flog2(x) * (1.0f/3.0f)) : 7.787f * x + 16.0f/116.0f;
            float fy = (y > 0.008856f) ? fexp2(flog2(y) * (1.0f/3.0f)) : 7.787f * y + 16.0f/116.0f;
            float fz = (z > 0.008856f) ? fexp2(flog2(z) * (1.0f/3.0f)) : 7.787f * z + 16.0f/116.0f;

            // sub-bin indices (scale/offset folded); ranges provably in [0,2048)
            int iL = (int)(2375.68f    * fy - 327.68f);
            int iA = (int)(4015.6863f  * (fx - fy) + 1028.01569f);
            int iB = (int)(1606.27451f * (fy - fz) + 1028.01569f);

            atomicAdd(&h[iL], 1u);
            atomicAdd(&h[NSUB + iA], 1u);
            atomicAdd(&h[2 * NSUB + iB], 1u);
        }
    }
    __syncthreads();

    // merge dual tables -> per-block partial, packed as u16 pairs (max 8192 < 2^16)
    unsigned* dst = part + (size_t)(b * BLKS_PER_IMG + bx) * PART_WORDS;
    for (int i = tid; i < PART_WORDS; i += THREADS1) {
        unsigned s0 = sh[0][2 * i]     + sh[1][2 * i];
        unsigned s1 = sh[0][2 * i + 1] + sh[1][2 * i + 1];
        dst[i] = s0 | (s1 << 16);
    }
    __threadfence();                       // flush partial to coherence point
    __syncthreads();
    if (tid == 0) {
        unsigned old = __hip_atomic_fetch_add(&done[b], 1u, __ATOMIC_ACQ_REL,
                                              __HIP_MEMORY_SCOPE_AGENT);
        lastFlag = (old == BLKS_PER_IMG - 1);
    }
    __syncthreads();
    if (!lastFlag) return;

    // ---- last block for image b: reduce 32 partials + conv + normalize ----
    float* sub3 = reinterpret_cast<float*>(&sh[0][0]);   // 6144 floats (24 KB)
    const unsigned long long* pimg = reinterpret_cast<const unsigned long long*>(
        part + (size_t)b * BLKS_PER_IMG * PART_WORDS);
    for (int w = tid; w < PART_WORDS / 2; w += THREADS1) {   // 1536 u64/partial
        unsigned s0 = 0, s1 = 0, s2 = 0, s3 = 0;
        #pragma unroll
        for (int k = 0; k < BLKS_PER_IMG; ++k) {
            unsigned long long v = __hip_atomic_load(
                &pimg[(size_t)k * (PART_WORDS / 2) + w],
                __ATOMIC_RELAXED, __HIP_MEMORY_SCOPE_AGENT);
            unsigned lo = (unsigned)v, hi = (unsigned)(v >> 32);
            s0 += lo & 0xFFFFu; s1 += lo >> 16;
            s2 += hi & 0xFFFFu; s3 += hi >> 16;
        }
        sub3[4 * w]     = (float)s0;       // exact: integer sums < 2^18
        sub3[4 * w + 1] = (float)s1;
        sub3[4 * w + 2] = (float)s2;
        sub3[4 * w + 3] = (float)s3;
    }
    __syncthreads();

    // d(s,j) = (s+0.5)/32 - 0.5 - j; 204 taps: s in [32j-86, 32j+117]
    const int j = tid >> 4;                // bin 0..63
    const int q = tid & 15;                // 16 lanes per bin
    const float C = 2.8853901f;            // 2/ln2
    const float jf = (float)j + 0.5f - (0.5f / 32.0f);
    const int s_lo = 32 * j - 86;
    #pragma unroll
    for (int ch = 0; ch < 3; ++ch) {
        float acc = 0.0f;
        #pragma unroll
        for (int i = 0; i < 13; ++i) {
            int s = s_lo + q + 16 * i;
            if (q + 16 * i < 204 && (unsigned)s < (unsigned)NSUB) {
                float d = (float)s * (1.0f / 32.0f) - jf;
                acc += sub3[ch * NSUB + s] * fexp2(-C * d * d);
            }
        }
        acc += __shfl_xor(acc, 1, 64);
        acc += __shfl_xor(acc, 2, 64);
        acc += __shfl_xor(acc, 4, 64);
        acc += __shfl_xor(acc, 8, 64);
        if (q == 0) hb[ch][j] = acc;
    }
    __syncthreads();

    if (tid < 192) {                       // 3 full waves: wave = channel
        const int ch = tid >> 6, bin = tid & 63;
        float v = hb[ch][bin];
        float s = v;
        #pragma unroll
        for (int off = 32; off >= 1; off >>= 1) s += __shfl_down(s, off, 64);
        s = __shfl(s, 0, 64);
        out[b * 192 + ch * 64 + bin] = v / (s + 1e-8f);
    }
}

extern "C" void kernel_launch(void* const* d_in, const int* in_sizes, int n_in,
                              void* d_out, int out_size, void* d_ws, size_t ws_size,
                              hipStream_t stream) {
    const float* img = (const float*)d_in[0];
    float* out     = (float*)d_out;
    unsigned* part = (unsigned*)d_ws;     // 16*32 partials * 3072 u32 = 6.3 MB

    const int B = in_sizes[0] / (3 * HW); // 16
    unsigned* done = part + (size_t)B * BLKS_PER_IMG * PART_WORDS;  // 64 B counters

    hipMemsetAsync(done, 0, B * sizeof(unsigned), stream);          // graph-capturable
    count_fused<<<dim3(BLKS_PER_IMG, B), THREADS1, 0, stream>>>(img, part, done, out);
}

// Round 3
// 89.439 us; speedup vs baseline: 2.9132x; 2.9132x over previous
//
#include <hip/hip_runtime.h>
#include <cmath>

#define HW (512*512)
#define NSUB 2048            // 64 bins x 32 sub-bins
#define THREADS1 1024
#define BLKS_PER_IMG 32

__device__ __forceinline__ float fexp2(float x) { return __builtin_amdgcn_exp2f(x); }
__device__ __forceinline__ float flog2(float x) { return __builtin_amdgcn_logf(x); }

// Phase 1: RGB -> Lab -> integer sub-bin counting into dual wave-parity LDS
// tables; then each block convolves ITS OWN sub-bin table down to 64 bins
// (conv is linear => distributes over blocks; identical 204-tap window) and
// stores a 192-float partial histogram. No fences, no atomics beyond LDS.
// Inter-kernel traffic: 393 KB instead of 6.3 MB.
__global__ __launch_bounds__(THREADS1) void count_conv_kernel(const float* __restrict__ img,
                                                              float* __restrict__ part) {
    __shared__ unsigned sh[2][3 * NSUB];   // 48 KB
    __shared__ float hb[3][64];
    const int tid = threadIdx.x;
    unsigned* flat = &sh[0][0];
    for (int i = tid; i < 2 * 3 * NSUB; i += THREADS1) flat[i] = 0u;
    __syncthreads();

    unsigned* h = sh[(tid >> 6) & 1];      // wave parity selects table

    const int b  = blockIdx.y;
    const int bx = blockIdx.x;
    const float* base = img + (size_t)b * 3u * HW;

    // one pass: 8 pixels/thread, all 6 float4 loads issued back-to-back
    // (32 blocks * 1024 threads * 8 px = 262144 = HW exactly)
    const int p = (bx * THREADS1 + tid) * 8;
    float4 r4a = *reinterpret_cast<const float4*>(base + p);
    float4 r4b = *reinterpret_cast<const float4*>(base + p + 4);
    float4 g4a = *reinterpret_cast<const float4*>(base + p + HW);
    float4 g4b = *reinterpret_cast<const float4*>(base + p + HW + 4);
    float4 b4a = *reinterpret_cast<const float4*>(base + p + 2 * HW);
    float4 b4b = *reinterpret_cast<const float4*>(base + p + 2 * HW + 4);
    float rr[8] = {r4a.x, r4a.y, r4a.z, r4a.w, r4b.x, r4b.y, r4b.z, r4b.w};
    float gg[8] = {g4a.x, g4a.y, g4a.z, g4a.w, g4b.x, g4b.y, g4b.z, g4b.w};
    float bl[8] = {b4a.x, b4a.y, b4a.z, b4a.w, b4b.x, b4b.y, b4b.z, b4b.w};

    #pragma unroll
    for (int k = 0; k < 8; ++k) {
        // sRGB -> linear (log2 inputs provably >= 0.09: no denormal risk)
        float lr = (rr[k] > 0.04045f) ? fexp2(2.4f * flog2((rr[k] + 0.055f) * (1.0f / 1.055f))) : rr[k] * (1.0f / 12.92f);
        float lg = (gg[k] > 0.04045f) ? fexp2(2.4f * flog2((gg[k] + 0.055f) * (1.0f / 1.055f))) : gg[k] * (1.0f / 12.92f);
        float lb = (bl[k] > 0.04045f) ? fexp2(2.4f * flog2((bl[k] + 0.055f) * (1.0f / 1.055f))) : bl[k] * (1.0f / 12.92f);

        // XYZ with xn/zn folded into the matrix rows
        float x = 0.4339530f * lr + 0.3762197f * lg + 0.1898288f * lb; // x/0.950456
        float y = 0.2126710f * lr + 0.7151600f * lg + 0.0721690f * lb;
        float z = 0.0177578f * lr + 0.1094766f * lg + 0.8727661f * lb; // z/1.088754

        float fx = (x > 0.008856f) ? fexp2(flog2(x) * (1.0f/3.0f)) : 7.787f * x + 16.0f/116.0f;
        float fy = (y > 0.008856f) ? fexp2(flog2(y) * (1.0f/3.0f)) : 7.787f * y + 16.0f/116.0f;
        float fz = (z > 0.008856f) ? fexp2(flog2(z) * (1.0f/3.0f)) : 7.787f * z + 16.0f/116.0f;

        // sub-bin indices (scale/offset folded); ranges provably in [0,2048)
        int iL = (int)(2375.68f    * fy - 327.68f);
        int iA = (int)(4015.6863f  * (fx - fy) + 1028.01569f);
        int iB = (int)(1606.27451f * (fy - fz) + 1028.01569f);

        atomicAdd(&h[iL], 1u);
        atomicAdd(&h[NSUB + iA], 1u);
        atomicAdd(&h[2 * NSUB + iB], 1u);
    }
    __syncthreads();

    // merge dual tables in place as float (each i owned by exactly one thread)
    float* subf = reinterpret_cast<float*>(&sh[0][0]);
    for (int i = tid; i < 3 * NSUB; i += THREADS1) {
        unsigned s = sh[0][i] + sh[1][i];          // <= 16384: exact in f32
        subf[i] = (float)s;
    }
    __syncthreads();

    // per-block conv: d(s,j) = (s+0.5)/32 - 0.5 - j; 204 taps: s in [32j-86, 32j+117]
    const int j = tid >> 4;                // bin 0..63
    const int q = tid & 15;                // 16 lanes per bin
    const float C = 2.8853901f;            // 2/ln2
    const float jf = (float)j + 0.5f - (0.5f / 32.0f);
    const int s_lo = 32 * j - 86;
    #pragma unroll
    for (int ch = 0; ch < 3; ++ch) {
        float acc = 0.0f;
        #pragma unroll
        for (int i = 0; i < 13; ++i) {
            int off = q + 16 * i;
            int s = s_lo + off;
            if (off < 204 && (unsigned)s < (unsigned)NSUB) {
                float d = (float)s * (1.0f / 32.0f) - jf;
                acc += subf[ch * NSUB + s] * fexp2(-C * d * d);
            }
        }
        acc += __shfl_xor(acc, 1, 64);
        acc += __shfl_xor(acc, 2, 64);
        acc += __shfl_xor(acc, 4, 64);
        acc += __shfl_xor(acc, 8, 64);
        if (q == 0) hb[ch][j] = acc;
    }
    __syncthreads();

    if (tid < 192) {                       // hb flat layout == output layout
        float* dst = part + (size_t)(b * BLKS_PER_IMG + bx) * 192;
        dst[tid] = (&hb[0][0])[tid];
    }
}

// Phase 2 (tiny): sum 32 partial 192-bin histograms per image, normalize per
// channel via wave reduction (wave == channel), write out. ~393 KB total read.
__global__ __launch_bounds__(192) void finalize_kernel(const float* __restrict__ part,
                                                       float* __restrict__ out) {
    const int b = blockIdx.x;
    const int t = threadIdx.x;             // 0..191; wave (t>>6) == channel
    const float* p0 = part + (size_t)b * BLKS_PER_IMG * 192 + t;
    float v = 0.0f;
    #pragma unroll
    for (int k = 0; k < BLKS_PER_IMG; ++k) v += p0[k * 192];
    float s = v;                           // per-channel sum across the wave's 64 bins
    #pragma unroll
    for (int off = 32; off >= 1; off >>= 1) s += __shfl_down(s, off, 64);
    s = __shfl(s, 0, 64);
    out[b * 192 + t] = v / (s + 1e-8f);
}

extern "C" void kernel_launch(void* const* d_in, const int* in_sizes, int n_in,
                              void* d_out, int out_size, void* d_ws, size_t ws_size,
                              hipStream_t stream) {
    const float* img = (const float*)d_in[0];
    float* out     = (float*)d_out;
    float* part    = (float*)d_ws;        // 16*32 partials * 192 f32 = 393 KB

    const int B = in_sizes[0] / (3 * HW); // 16

    count_conv_kernel<<<dim3(BLKS_PER_IMG, B), THREADS1, 0, stream>>>(img, part);
    finalize_kernel<<<B, 192, 0, stream>>>(part, out);
}

// Round 4
// 87.440 us; speedup vs baseline: 2.9798x; 1.0229x over previous
//
#include <hip/hip_runtime.h>
#include <cmath>

#define HW (512*512)
#define NSUB 2048            // 64 bins x 32 sub-bins
#define THREADS1 1024
#define BLKS_PER_IMG 32
#define PART_WORDS (3 * NSUB / 2)   // 3072 u32 per partial (u16-packed sub-bins)
#define TBL (3 * NSUB + 1)          // +1 word skew: same index -> adjacent bank

__device__ __forceinline__ float fexp2(float x) { return __builtin_amdgcn_exp2f(x); }
__device__ __forceinline__ float flog2(float x) { return __builtin_amdgcn_logf(x); }

// Phase 1: RGB -> Lab -> integer sub-bin counting into dual LANE-parity LDS
// tables (table 1 skewed +1 word so equal sub-bin indices land on adjacent
// banks: a hot bin's m lanes split m/2+m/2 across two banks; 2-way is free).
// Per-block partial stored as u16 pairs (max count/block 8192 < 2^16).
__global__ __launch_bounds__(THREADS1) void count_kernel(const float* __restrict__ img,
                                                         unsigned* __restrict__ part) {
    __align__(16) __shared__ unsigned sh[2 * TBL + 2];   // ~48 KB
    const int tid = threadIdx.x;
    {   // vectorized zero-init (ds_write_b128)
        uint4* z = reinterpret_cast<uint4*>(sh);
        const uint4 zero = {0u, 0u, 0u, 0u};
        for (int i = tid; i < (2 * TBL + 2) / 4; i += THREADS1) z[i] = zero;
    }
    __syncthreads();

    unsigned* h = sh + (tid & 1) * TBL;    // lane parity selects skewed table

    const int b  = blockIdx.y;
    const int bx = blockIdx.x;
    const float* base = img + (size_t)b * 3u * HW;

    // one pass: 8 pixels/thread, all 6 float4 loads issued back-to-back
    // (32 blocks * 1024 threads * 8 px = 262144 = HW exactly)
    const int p = (bx * THREADS1 + tid) * 8;
    float4 r4a = *reinterpret_cast<const float4*>(base + p);
    float4 r4b = *reinterpret_cast<const float4*>(base + p + 4);
    float4 g4a = *reinterpret_cast<const float4*>(base + p + HW);
    float4 g4b = *reinterpret_cast<const float4*>(base + p + HW + 4);
    float4 b4a = *reinterpret_cast<const float4*>(base + p + 2 * HW);
    float4 b4b = *reinterpret_cast<const float4*>(base + p + 2 * HW + 4);
    float rr[8] = {r4a.x, r4a.y, r4a.z, r4a.w, r4b.x, r4b.y, r4b.z, r4b.w};
    float gg[8] = {g4a.x, g4a.y, g4a.z, g4a.w, g4b.x, g4b.y, g4b.z, g4b.w};
    float bl[8] = {b4a.x, b4a.y, b4a.z, b4a.w, b4b.x, b4b.y, b4b.z, b4b.w};

    #pragma unroll
    for (int k = 0; k < 8; ++k) {
        // sRGB -> linear (log2 inputs provably >= 0.09: no denormal risk)
        float lr = (rr[k] > 0.04045f) ? fexp2(2.4f * flog2((rr[k] + 0.055f) * (1.0f / 1.055f))) : rr[k] * (1.0f / 12.92f);
        float lg = (gg[k] > 0.04045f) ? fexp2(2.4f * flog2((gg[k] + 0.055f) * (1.0f / 1.055f))) : gg[k] * (1.0f / 12.92f);
        float lb = (bl[k] > 0.04045f) ? fexp2(2.4f * flog2((bl[k] + 0.055f) * (1.0f / 1.055f))) : bl[k] * (1.0f / 12.92f);

        // XYZ with xn/zn folded into the matrix rows
        float x = 0.4339530f * lr + 0.3762197f * lg + 0.1898288f * lb; // x/0.950456
        float y = 0.2126710f * lr + 0.7151600f * lg + 0.0721690f * lb;
        float z = 0.0177578f * lr + 0.1094766f * lg + 0.8727661f * lb; // z/1.088754

        float fx = (x > 0.008856f) ? fexp2(flog2(x) * (1.0f/3.0f)) : 7.787f * x + 16.0f/116.0f;
        float fy = (y > 0.008856f) ? fexp2(flog2(y) * (1.0f/3.0f)) : 7.787f * y + 16.0f/116.0f;
        float fz = (z > 0.008856f) ? fexp2(flog2(z) * (1.0f/3.0f)) : 7.787f * z + 16.0f/116.0f;

        // sub-bin indices (scale/offset folded); ranges provably in [0,2048)
        int iL = (int)(2375.68f    * fy - 327.68f);
        int iA = (int)(4015.6863f  * (fx - fy) + 1028.01569f);
        int iB = (int)(1606.27451f * (fy - fz) + 1028.01569f);

        atomicAdd(&h[iL], 1u);
        atomicAdd(&h[NSUB + iA], 1u);
        atomicAdd(&h[2 * NSUB + iB], 1u);
    }
    __syncthreads();

    // merge dual tables -> per-block partial, packed as u16 pairs
    unsigned* dst = part + (size_t)(b * BLKS_PER_IMG + bx) * PART_WORDS;
    for (int i = tid; i < PART_WORDS; i += THREADS1) {
        unsigned s0 = sh[2 * i]     + sh[TBL + 2 * i];
        unsigned s1 = sh[2 * i + 1] + sh[TBL + 2 * i + 1];
        dst[i] = s0 | (s1 << 16);
    }
}

// Phase 2: reduce 32 u16-packed partials (1024 threads, 1 packed word each),
// truncated Gaussian conv -> 64 bins (16 lanes/bin x 10 taps = 160-tap window,
// +-2.5 bins = 5 sigma, truncation error < 1e-5), normalize.
__global__ __launch_bounds__(1024) void conv_norm_kernel(const unsigned* __restrict__ part,
                                                         float* __restrict__ out) {
    __shared__ float sub[NSUB];
    __shared__ float hb[64];
    const int img = blockIdx.x / 3;
    const int ch  = blockIdx.x % 3;
    const int t   = threadIdx.x;           // u32 word index 0..1023 within channel

    const unsigned* p0 = part + (size_t)img * BLKS_PER_IMG * PART_WORDS
                              + (size_t)ch * (NSUB / 2) + t;
    unsigned s0 = 0, s1 = 0;
    #pragma unroll
    for (int k = 0; k < BLKS_PER_IMG; ++k) {
        unsigned v = p0[(size_t)k * PART_WORDS];
        s0 += v & 0xFFFFu;
        s1 += v >> 16;
    }
    sub[2 * t]     = (float)s0;            // exact: integer sums < 2^24
    sub[2 * t + 1] = (float)s1;
    __syncthreads();

    // d(s,j) = (s+0.5)/32 - 0.5 - j; 160 taps: s in [32j-64, 32j+95]
    const int j = t >> 4;                  // bin 0..63
    const int q = t & 15;                  // 16 lanes per bin
    const float C = 2.8853901f;            // 2/ln2
    const float jf = (float)j + 0.5f - (0.5f / 32.0f);
    const int s_lo = 32 * j - 64;
    float acc = 0.0f;
    #pragma unroll
    for (int i = 0; i < 10; ++i) {
        int m = i + (j % 10); if (m >= 10) m -= 10;   // de-bank: 16m parity alternates with j
        int s = s_lo + q + 16 * m;
        if ((unsigned)s < (unsigned)NSUB) {
            float d = (float)s * (1.0f / 32.0f) - jf;
            acc += sub[s] * fexp2(-C * d * d);
        }
    }
    acc += __shfl_xor(acc, 1, 64);
    acc += __shfl_xor(acc, 2, 64);
    acc += __shfl_xor(acc, 4, 64);
    acc += __shfl_xor(acc, 8, 64);
    if (q == 0) hb[j] = acc;
    __syncthreads();

    if (t < 64) {
        float v = hb[t];
        float s = v;
        #pragma unroll
        for (int off = 32; off >= 1; off >>= 1) s += __shfl_down(s, off, 64);
        s = __shfl(s, 0, 64);
        out[img * 192 + ch * 64 + t] = v / (s + 1e-8f);
    }
}

extern "C" void kernel_launch(void* const* d_in, const int* in_sizes, int n_in,
                              void* d_out, int out_size, void* d_ws, size_t ws_size,
                              hipStream_t stream) {
    const float* img = (const float*)d_in[0];
    float* out     = (float*)d_out;
    unsigned* part = (unsigned*)d_ws;     // 16*32 partials * 3072 u32 = 6.3 MB

    const int B = in_sizes[0] / (3 * HW); // 16

    count_kernel<<<dim3(BLKS_PER_IMG, B), THREADS1, 0, stream>>>(img, part);
    conv_norm_kernel<<<B * 3, 1024, 0, stream>>>(part, out);
}

// Round 5
// 87.400 us; speedup vs baseline: 2.9812x; 1.0005x over previous
//
#include <hip/hip_runtime.h>
#include <cmath>

#define HW (512*512)
#define NSUB 2048            // 64 bins x 32 sub-bins
#define THREADS1 1024
#define BLKS_PER_IMG 32
#define TBL (3 * NSUB + 1)   // +1 word skew: same index -> adjacent bank
#define NTAP 160             // +-2.5 bins = 5 sigma; truncation < 5e-6

__device__ __forceinline__ float fexp2(float x) { return __builtin_amdgcn_exp2f(x); }
__device__ __forceinline__ float flog2(float x) { return __builtin_amdgcn_logf(x); }

// Fused phase 1: RGB -> Lab -> integer sub-bin counting into dual lane-parity
// skewed LDS tables, then per-block 160-tap conv to 64 bins using a
// PRECOMPUTED weight table (conv weight depends only on tap offset:
// w(o) = exp2(-C*((o+0.5)/32-0.5)^2) -- 160 exp2 per block instead of 10240,
// which is what made the r3 fusion lose). Emits 192-float partial histogram;
// conv is linear so summing partials over blocks == conv of summed sub-bins.
__global__ __launch_bounds__(THREADS1) void count_conv_kernel(const float* __restrict__ img,
                                                              float* __restrict__ part) {
    __align__(16) __shared__ unsigned sh[2 * TBL + 2];   // ~48 KB; reused as float subf
    __shared__ float W[NTAP];
    __shared__ float hb[3][64];
    const int tid = threadIdx.x;
    {   // vectorized zero-init (ds_write_b128)
        uint4* z = reinterpret_cast<uint4*>(sh);
        const uint4 zero = {0u, 0u, 0u, 0u};
        for (int i = tid; i < (2 * TBL + 2) / 4; i += THREADS1) z[i] = zero;
    }
    if (tid < NTAP) {        // weight table: W[t], offset o = t-64 from bin base
        const float C = 2.8853901f;          // 2/ln2
        float d = ((float)tid - 63.5f) * (1.0f / 32.0f) - 0.5f;
        W[tid] = fexp2(-C * d * d);
    }
    __syncthreads();

    unsigned* h = sh + (tid & 1) * TBL;    // lane parity selects skewed table

    const int b  = blockIdx.y;
    const int bx = blockIdx.x;
    const float* base = img + (size_t)b * 3u * HW;

    // one pass: 8 pixels/thread, all 6 float4 loads issued back-to-back
    // (32 blocks * 1024 threads * 8 px = 262144 = HW exactly)
    const int p = (bx * THREADS1 + tid) * 8;
    float4 r4a = *reinterpret_cast<const float4*>(base + p);
    float4 r4b = *reinterpret_cast<const float4*>(base + p + 4);
    float4 g4a = *reinterpret_cast<const float4*>(base + p + HW);
    float4 g4b = *reinterpret_cast<const float4*>(base + p + HW + 4);
    float4 b4a = *reinterpret_cast<const float4*>(base + p + 2 * HW);
    float4 b4b = *reinterpret_cast<const float4*>(base + p + 2 * HW + 4);
    float rr[8] = {r4a.x, r4a.y, r4a.z, r4a.w, r4b.x, r4b.y, r4b.z, r4b.w};
    float gg[8] = {g4a.x, g4a.y, g4a.z, g4a.w, g4b.x, g4b.y, g4b.z, g4b.w};
    float bl[8] = {b4a.x, b4a.y, b4a.z, b4a.w, b4b.x, b4b.y, b4b.z, b4b.w};

    #pragma unroll
    for (int k = 0; k < 8; ++k) {
        // sRGB -> linear (log2 inputs provably >= 0.09: no denormal risk)
        float lr = (rr[k] > 0.04045f) ? fexp2(2.4f * flog2((rr[k] + 0.055f) * (1.0f / 1.055f))) : rr[k] * (1.0f / 12.92f);
        float lg = (gg[k] > 0.04045f) ? fexp2(2.4f * flog2((gg[k] + 0.055f) * (1.0f / 1.055f))) : gg[k] * (1.0f / 12.92f);
        float lb = (bl[k] > 0.04045f) ? fexp2(2.4f * flog2((bl[k] + 0.055f) * (1.0f / 1.055f))) : bl[k] * (1.0f / 12.92f);

        // XYZ with xn/zn folded into the matrix rows
        float x = 0.4339530f * lr + 0.3762197f * lg + 0.1898288f * lb; // x/0.950456
        float y = 0.2126710f * lr + 0.7151600f * lg + 0.0721690f * lb;
        float z = 0.0177578f * lr + 0.1094766f * lg + 0.8727661f * lb; // z/1.088754

        float fx = (x > 0.008856f) ? fexp2(flog2(x) * (1.0f/3.0f)) : 7.787f * x + 16.0f/116.0f;
        float fy = (y > 0.008856f) ? fexp2(flog2(y) * (1.0f/3.0f)) : 7.787f * y + 16.0f/116.0f;
        float fz = (z > 0.008856f) ? fexp2(flog2(z) * (1.0f/3.0f)) : 7.787f * z + 16.0f/116.0f;

        // sub-bin indices (scale/offset folded); ranges provably in [0,2048)
        int iL = (int)(2375.68f    * fy - 327.68f);
        int iA = (int)(4015.6863f  * (fx - fy) + 1028.01569f);
        int iB = (int)(1606.27451f * (fy - fz) + 1028.01569f);

        atomicAdd(&h[iL], 1u);
        atomicAdd(&h[NSUB + iA], 1u);
        atomicAdd(&h[2 * NSUB + iB], 1u);
    }
    __syncthreads();

    // merge dual tables in place as float over table-0 storage (index i's
    // read+write stay in one thread; table-1 slots are never overwritten)
    float* subf = reinterpret_cast<float*>(sh);
    for (int i = tid; i < 3 * NSUB; i += THREADS1) {
        unsigned s = sh[i] + sh[TBL + i];          // <= 16384: exact in f32
        subf[i] = (float)s;
    }
    __syncthreads();

    // per-block conv via weight table: s = 32j - 64 + t, t = q + 16i
    // W[] reads: same-address broadcast (free); subf[] reads: 2 lanes/bank (free)
    const int j = tid >> 4;                // bin 0..63
    const int q = tid & 15;                // 16 lanes per bin
    const int s_lo = 32 * j - 64;
    #pragma unroll
    for (int ch = 0; ch < 3; ++ch) {
        float acc = 0.0f;
        #pragma unroll
        for (int i = 0; i < 10; ++i) {
            int t = q + 16 * i;
            int s = s_lo + t;
            if ((unsigned)s < (unsigned)NSUB)
                acc += subf[ch * NSUB + s] * W[t];
        }
        acc += __shfl_xor(acc, 1, 64);
        acc += __shfl_xor(acc, 2, 64);
        acc += __shfl_xor(acc, 4, 64);
        acc += __shfl_xor(acc, 8, 64);
        if (q == 0) hb[ch][j] = acc;
    }
    __syncthreads();

    if (tid < 192) {                       // hb flat layout == output layout
        float* dst = part + (size_t)(b * BLKS_PER_IMG + bx) * 192;
        dst[tid] = (&hb[0][0])[tid];
    }
}

// Phase 2 (tiny): sum 32 partial 192-bin histograms per image, normalize per
// channel via wave reduction (wave == channel), write out. ~393 KB total read.
__global__ __launch_bounds__(192) void finalize_kernel(const float* __restrict__ part,
                                                       float* __restrict__ out) {
    const int b = blockIdx.x;
    const int t = threadIdx.x;             // 0..191; wave (t>>6) == channel
    const float* p0 = part + (size_t)b * BLKS_PER_IMG * 192 + t;
    float v = 0.0f;
    #pragma unroll
    for (int k = 0; k < BLKS_PER_IMG; ++k) v += p0[k * 192];
    float s = v;                           // per-channel sum across the wave's 64 bins
    #pragma unroll
    for (int off = 32; off >= 1; off >>= 1) s += __shfl_down(s, off, 64);
    s = __shfl(s, 0, 64);
    out[b * 192 + t] = v / (s + 1e-8f);
}

extern "C" void kernel_launch(void* const* d_in, const int* in_sizes, int n_in,
                              void* d_out, int out_size, void* d_ws, size_t ws_size,
                              hipStream_t stream) {
    const float* img = (const float*)d_in[0];
    float* out     = (float*)d_out;
    float* part    = (float*)d_ws;        // 16*32 partials * 192 f32 = 393 KB

    const int B = in_sizes[0] / (3 * HW); // 16

    count_conv_kernel<<<dim3(BLKS_PER_IMG, B), THREADS1, 0, stream>>>(img, part);
    finalize_kernel<<<B, 192, 0, stream>>>(part, out);
}